// Round 8
// baseline (224.052 us; speedup 1.0000x reference)
//
#include <hip/hip_runtime.h>
#include <cstdint>
#include <cstddef>

// Problem constants (SparseLinear: B=4096, IN=4096, OUT=4096, NNZ=1677722)
#define IN_F  4096
#define OUT_F 4096
#define BATCH 4096

typedef __bf16 bf16_t;
typedef __bf16 bf16x8 __attribute__((ext_vector_type(8)));
typedef float  f32x4  __attribute__((ext_vector_type(4)));

// ---------------------------------------------------------------------------
// f32 -> bf16 round-to-nearest-even (bit trick, deterministic)
// ---------------------------------------------------------------------------
__device__ __forceinline__ unsigned short f32_to_bf16_rne(float f) {
  union { float f; unsigned int u; } v;
  v.f = f;
  unsigned int u = v.u;
  return (unsigned short)((u + 0x7FFFu + ((u >> 16) & 1u)) >> 16);
}

__device__ __forceinline__ uint4 cvt8(float4 a, float4 b) {
  uint4 o;
  o.x = (unsigned)f32_to_bf16_rne(a.x) | ((unsigned)f32_to_bf16_rne(a.y) << 16);
  o.y = (unsigned)f32_to_bf16_rne(a.z) | ((unsigned)f32_to_bf16_rne(a.w) << 16);
  o.z = (unsigned)f32_to_bf16_rne(b.x) | ((unsigned)f32_to_bf16_rne(b.y) << 16);
  o.w = (unsigned)f32_to_bf16_rne(b.z) | ((unsigned)f32_to_bf16_rne(b.w) << 16);
  return o;
}

// ---------------------------------------------------------------------------
// Fused: zero the bf16 W buffer AND convert x -> bf16. Grid-stride.
// ---------------------------------------------------------------------------
#define WU16 ((OUT_F * IN_F) / 8)     // 16B units of Wbf (2097152)
#define XUNITS ((BATCH * IN_F) / 8)   // 8-elem units of x (2097152)

__global__ __launch_bounds__(256) void init_zero_cvtx(
    uint4* __restrict__ Wbfv, const float4* __restrict__ xin,
    uint4* __restrict__ xbf) {
  const uint4 z = {0u, 0u, 0u, 0u};
  for (int u = blockIdx.x * 256 + threadIdx.x; u < WU16 + XUNITS;
       u += gridDim.x * 256) {
    if (u < WU16) {
      Wbfv[u] = z;
    } else {
      const int i = u - WU16;
      xbf[i] = cvt8(xin[2 * i], xin[2 * i + 1]);
    }
  }
}

// ---------------------------------------------------------------------------
// Scatter-add COO weights directly into bf16 W (packed-bf16 atomic add).
// Duplicates still sum (coalesce semantics). mask is int32 on device (R1).
// ---------------------------------------------------------------------------
__global__ __launch_bounds__(256) void scatter_bf16(
    const float* __restrict__ w, const int* __restrict__ rows,
    const int* __restrict__ cols, const int* __restrict__ mask,
    unsigned* __restrict__ Wpk, int nnz) {
  int i = blockIdx.x * 256 + threadIdx.x;
  if (i >= nnz) return;
  if (mask[i] == 0) return;
  const unsigned h = f32_to_bf16_rne(w[i]);
  const size_t e = (size_t)rows[i] * IN_F + cols[i];
  const unsigned data = (e & 1) ? (h << 16) : h;
  unsigned* p = Wpk + (e >> 1);
  asm volatile("global_atomic_pk_add_bf16 %0, %1, off"
               :: "v"(p), "v"(data) : "memory");
}

// ---------------------------------------------------------------------------
// 256x256 bf16 GEMM, C = A @ Bm^T (row-major [4096][4096]).
// R7/R8: REGISTER-DOUBLE-BUFFERED READ-AHEAD (R7 had a macro mechanics bug:
// object-like set macros aren't expanded before argument binding; now the
// set TAG is pasted with ##). R5 (vmcnt slack) and R6 (barrier count) were
// flat -> stall is lgkm exposure: ds_reads issued just before BAR had only
// the barrier-crossing to complete before lgkmcnt(0). Now phase p issues the
// ds_reads for phase p+1 into the ALTERNATE register set and waits with
// PARTIAL lgkmcnt(12): the older set (consumed now) is drained, the 12
// just-issued stay in flight and complete under this phase's 32 MFMA.
// Ledger (iter i, t=2i, kb=128i; VM(4) at EVERY phase end):
//   P1 consume SetA=t.ks0   | readahead SetB<-t.ks1   | stage t+1.ks1
//   P2 consume SetB=t.ks1   | readahead SetA<-t+1.ks0 | stage t+2.ks0
//   P3 consume SetA=t+1.ks0 | readahead SetB<-t+1.ks1 | stage t+2.ks1
//   P4 consume SetB=t+1.ks1 | readahead SetA<-t+2.ks0 | stage t+3.ks0
// Landed-proofs: readahead src staged P-3, VM(4)@P-2-end + BAR => landed
// before issue. Drain-proofs: reads issued at p drain at lgkm(12) of p+1,
// region overwritten earliest p+2, >=1 barrier after. All edges verified.
// T1 XCD swizzle + T2 decorrelated swizzle (R4: 0 conflicts) + T5 setprio.
// ---------------------------------------------------------------------------
#define A0_B 0
#define B0_B 32768
#define A1_B 65536
#define B1_B 98304
#define HALF 16384

#define STAGE(Xg, kpos, ldsbase) do {                                          \
  __builtin_amdgcn_global_load_lds(                                            \
    (const __attribute__((address_space(1))) void*)((Xg) + (size_t)srow * 4096 + (kpos) + schunk), \
    (__attribute__((address_space(3))) void*)(lds + (ldsbase) + tid * 16), 16, 0, 0); \
  __builtin_amdgcn_global_load_lds(                                            \
    (const __attribute__((address_space(1))) void*)((Xg) + (size_t)(srow + 128) * 4096 + (kpos) + schunk), \
    (__attribute__((address_space(3))) void*)(lds + (ldsbase) + 8192 + tid * 16), 16, 0, 0); \
} while (0)

// 12 ds_read_b128 into register set S (token-pasted names a<S>0..7, b<S>0..3)
#define RDSET(ab, bb, S) do {                                                  \
  a##S##0 = *(const bf16x8*)(lds + (ab) + offA[0][0]);                         \
  a##S##1 = *(const bf16x8*)(lds + (ab) + offA[0][1]);                         \
  a##S##2 = *(const bf16x8*)(lds + (ab) + offA[0][2]);                         \
  a##S##3 = *(const bf16x8*)(lds + (ab) + offA[0][3]);                         \
  a##S##4 = *(const bf16x8*)(lds + (ab) + offA[1][0]);                         \
  a##S##5 = *(const bf16x8*)(lds + (ab) + offA[1][1]);                         \
  a##S##6 = *(const bf16x8*)(lds + (ab) + offA[1][2]);                         \
  a##S##7 = *(const bf16x8*)(lds + (ab) + offA[1][3]);                         \
  b##S##0 = *(const bf16x8*)(lds + (bb) + offB[0]);                            \
  b##S##1 = *(const bf16x8*)(lds + (bb) + offB[1]);                            \
  b##S##2 = *(const bf16x8*)(lds + (bb) + offB[2]);                            \
  b##S##3 = *(const bf16x8*)(lds + (bb) + offB[3]);                            \
} while (0)

#define MQ(mh, A0_,A1_,A2_,A3_, B0_,B1_,B2_,B3_) do {                          \
  acc[(mh)*4+0][0] = __builtin_amdgcn_mfma_f32_16x16x32_bf16(A0_, B0_, acc[(mh)*4+0][0], 0, 0, 0); \
  acc[(mh)*4+0][1] = __builtin_amdgcn_mfma_f32_16x16x32_bf16(A0_, B1_, acc[(mh)*4+0][1], 0, 0, 0); \
  acc[(mh)*4+0][2] = __builtin_amdgcn_mfma_f32_16x16x32_bf16(A0_, B2_, acc[(mh)*4+0][2], 0, 0, 0); \
  acc[(mh)*4+0][3] = __builtin_amdgcn_mfma_f32_16x16x32_bf16(A0_, B3_, acc[(mh)*4+0][3], 0, 0, 0); \
  acc[(mh)*4+1][0] = __builtin_amdgcn_mfma_f32_16x16x32_bf16(A1_, B0_, acc[(mh)*4+1][0], 0, 0, 0); \
  acc[(mh)*4+1][1] = __builtin_amdgcn_mfma_f32_16x16x32_bf16(A1_, B1_, acc[(mh)*4+1][1], 0, 0, 0); \
  acc[(mh)*4+1][2] = __builtin_amdgcn_mfma_f32_16x16x32_bf16(A1_, B2_, acc[(mh)*4+1][2], 0, 0, 0); \
  acc[(mh)*4+1][3] = __builtin_amdgcn_mfma_f32_16x16x32_bf16(A1_, B3_, acc[(mh)*4+1][3], 0, 0, 0); \
  acc[(mh)*4+2][0] = __builtin_amdgcn_mfma_f32_16x16x32_bf16(A2_, B0_, acc[(mh)*4+2][0], 0, 0, 0); \
  acc[(mh)*4+2][1] = __builtin_amdgcn_mfma_f32_16x16x32_bf16(A2_, B1_, acc[(mh)*4+2][1], 0, 0, 0); \
  acc[(mh)*4+2][2] = __builtin_amdgcn_mfma_f32_16x16x32_bf16(A2_, B2_, acc[(mh)*4+2][2], 0, 0, 0); \
  acc[(mh)*4+2][3] = __builtin_amdgcn_mfma_f32_16x16x32_bf16(A2_, B3_, acc[(mh)*4+2][3], 0, 0, 0); \
  acc[(mh)*4+3][0] = __builtin_amdgcn_mfma_f32_16x16x32_bf16(A3_, B0_, acc[(mh)*4+3][0], 0, 0, 0); \
  acc[(mh)*4+3][1] = __builtin_amdgcn_mfma_f32_16x16x32_bf16(A3_, B1_, acc[(mh)*4+3][1], 0, 0, 0); \
  acc[(mh)*4+3][2] = __builtin_amdgcn_mfma_f32_16x16x32_bf16(A3_, B2_, acc[(mh)*4+3][2], 0, 0, 0); \
  acc[(mh)*4+3][3] = __builtin_amdgcn_mfma_f32_16x16x32_bf16(A3_, B3_, acc[(mh)*4+3][3], 0, 0, 0); \
} while (0)

#define MFMA32S(S) do {                                                        \
  MQ(0, a##S##0,a##S##1,a##S##2,a##S##3, b##S##0,b##S##1,b##S##2,b##S##3);     \
  MQ(1, a##S##4,a##S##5,a##S##6,a##S##7, b##S##0,b##S##1,b##S##2,b##S##3);     \
} while (0)

#define BAR()    __builtin_amdgcn_s_barrier()
#define LGKMW(n) do { asm volatile("s_waitcnt lgkmcnt(" #n ")" ::: "memory");  \
                      __builtin_amdgcn_sched_barrier(0); } while (0)
#define VM(n)    asm volatile("s_waitcnt vmcnt(" #n ")" ::: "memory")
#define PRIO1()  __builtin_amdgcn_s_setprio(1)
#define PRIO0()  __builtin_amdgcn_s_setprio(0)

__global__ __launch_bounds__(512, 2) void gemm_bt_ra(
    const bf16_t* __restrict__ A, const bf16_t* __restrict__ Bm,
    float* __restrict__ C) {
  __shared__ __align__(16) char lds[131072];

  const int tid  = threadIdx.x;
  const int lane = tid & 63;
  const int wave = tid >> 6;
  const int wm   = wave >> 2;  // 0..1  (M half of block)
  const int wn   = wave & 3;   // 0..3  (N quarter of block)

  // T1: XCD-aware swizzle; 256 blocks % 8 == 0 -> bijective
  const int sbid = (blockIdx.x & 7) * 32 + (blockIdx.x >> 3);
  const int bm   = sbid >> 4;
  const int bn   = sbid & 15;

  const int frow = lane & 15;
  const int c16  = (lane >> 4) * 16;  // 16B chunk within 64B row

  // ds_read byte offsets within a ks-half [256][32] region (T2-swizzled,
  // decorrelated: XOR with row bits 1-2; R4-verified 0 conflicts)
  int offA[2][4], offB[4];
#pragma unroll
  for (int mh = 0; mh < 2; ++mh)
#pragma unroll
    for (int mi = 0; mi < 4; ++mi) {
      int r = wm * 128 + mh * 64 + mi * 16 + frow;
      offA[mh][mi] = r * 64 + (c16 ^ (((r >> 1) & 3) << 4));
    }
#pragma unroll
  for (int ni = 0; ni < 4; ++ni) {
    int r = wn * 64 + ni * 16 + frow;
    offB[ni] = r * 64 + (c16 ^ (((r >> 1) & 3) << 4));
  }

  // staging: write-side inverse of the read swizzle ((srow+128) keeps the
  // same ((row>>1)&3): bit7 is stripped by &3)
  const int srow   = tid >> 2;
  const int schunk = ((tid & 3) ^ ((srow >> 1) & 3)) * 8;
  const bf16_t* Ag = A  + (size_t)bm * 256 * 4096;
  const bf16_t* Bg = Bm + (size_t)bn * 256 * 4096;

  f32x4 acc[8][4] = {};
  bf16x8 aA0, aA1, aA2, aA3, aA4, aA5, aA6, aA7, bA0, bA1, bA2, bA3;
  bf16x8 aB0, aB1, aB2, aB3, aB4, aB5, aB6, aB7, bB0, bB1, bB2, bB3;

  // ---- prologue: stage t0 (both halves) + t1.ks0; drain t0, pre-read SetA.
  STAGE(Ag, 0,  A0_B);
  STAGE(Bg, 0,  B0_B);
  STAGE(Ag, 32, A0_B + HALF);
  STAGE(Bg, 32, B0_B + HALF);
  STAGE(Ag, 64, A1_B);
  STAGE(Bg, 64, B1_B);
  VM(4);                       // t0 landed; t1.ks0 (4) still in flight
  BAR();
  RDSET(A0_B, B0_B, A);        // pre-read t0.ks0 -> SetA

  int kb = 0;
#pragma unroll 1
  for (int i = 0; i < 31; ++i, kb += 128) {
    // P1: consume SetA (t.ks0) | readahead SetB <- t.ks1 | stage t+1.ks1
    RDSET(A0_B + HALF, B0_B + HALF, B);
    STAGE(Ag, kb + 96, A1_B + HALF);
    STAGE(Bg, kb + 96, B1_B + HALF);
    BAR(); LGKMW(12); PRIO1(); MFMA32S(A); PRIO0(); VM(4); BAR();
    // P2: consume SetB (t.ks1) | readahead SetA <- t+1.ks0 | stage t+2.ks0
    RDSET(A1_B, B1_B, A);
    STAGE(Ag, kb + 128, A0_B);
    STAGE(Bg, kb + 128, B0_B);
    BAR(); LGKMW(12); PRIO1(); MFMA32S(B); PRIO0(); VM(4); BAR();
    // P3: consume SetA (t+1.ks0) | readahead SetB <- t+1.ks1 | stage t+2.ks1
    RDSET(A1_B + HALF, B1_B + HALF, B);
    STAGE(Ag, kb + 160, A0_B + HALF);
    STAGE(Bg, kb + 160, B0_B + HALF);
    BAR(); LGKMW(12); PRIO1(); MFMA32S(A); PRIO0(); VM(4); BAR();
    // P4: consume SetB (t+1.ks1) | readahead SetA <- t+2.ks0 | stage t+3.ks0
    RDSET(A0_B, B0_B, A);
    STAGE(Ag, kb + 192, A1_B);
    STAGE(Bg, kb + 192, B1_B);
    BAR(); LGKMW(12); PRIO1(); MFMA32S(B); PRIO0(); VM(4); BAR();
  }

  // ---- peeled final iter (t=62,63; kb == 3968)
  // P1: consume SetA (t62.ks0) | readahead SetB <- t62.ks1 | stage t63.ks1
  RDSET(A0_B + HALF, B0_B + HALF, B);
  STAGE(Ag, 4064, A1_B + HALF);
  STAGE(Bg, 4064, B1_B + HALF);
  BAR(); LGKMW(12); PRIO1(); MFMA32S(A); PRIO0(); VM(4); BAR();
  // P2: consume SetB (t62.ks1) | readahead SetA <- t63.ks0 | full drain
  RDSET(A1_B, B1_B, A);
  BAR(); LGKMW(12); PRIO1(); MFMA32S(B); PRIO0(); VM(0); BAR();
  // P3: consume SetA (t63.ks0) | readahead SetB <- t63.ks1 (landed: VM(0))
  RDSET(A1_B + HALF, B1_B + HALF, B);
  BAR(); LGKMW(12); PRIO1(); MFMA32S(A); PRIO0(); BAR();
  // P4: consume SetB (t63.ks1)
  LGKMW(0); PRIO1(); MFMA32S(B); PRIO0();

  // ---- C write (D layout: col = lane&15, row = (lane>>4)*4 + jj)
#pragma unroll
  for (int mh = 0; mh < 2; ++mh)
#pragma unroll
    for (int mi = 0; mi < 4; ++mi)
#pragma unroll
      for (int ni = 0; ni < 4; ++ni) {
        const int row = bm * 256 + wm * 128 + mh * 64 + mi * 16 + (lane >> 4) * 4;
        const int col = bn * 256 + wn * 64 + ni * 16 + frow;
#pragma unroll
        for (int jj = 0; jj < 4; ++jj)
          C[(size_t)(row + jj) * 4096 + col] = acc[mh * 4 + mi][ni][jj];
      }
}

// ---------------------------------------------------------------------------
extern "C" void kernel_launch(void* const* d_in, const int* in_sizes, int n_in,
                              void* d_out, int out_size, void* d_ws, size_t ws_size,
                              hipStream_t stream) {
  const float* x     = (const float*)d_in[0];
  const float* wvals = (const float*)d_in[1];
  const int*   idx   = (const int*)d_in[2];   // (2, nnz): rows then cols
  const int*   mk    = (const int*)d_in[3];   // bool -> int32 on device (R1)
  const int    nnz   = in_sizes[1];

  // ws: [0,32MB) = W bf16, [32MB,64MB) = x bf16.
  bf16_t* Wbf = (bf16_t*)d_ws;
  bf16_t* xbf = (bf16_t*)((char*)d_ws + (size_t)OUT_F * IN_F * sizeof(bf16_t));

  const size_t needed = (size_t)OUT_F * IN_F * 2 + (size_t)BATCH * IN_F * 2;
  if (ws_size < needed) return;

  // 1. fused: zero bf16 W + convert x -> bf16
  init_zero_cvtx<<<2048, 256, 0, stream>>>(
      (uint4*)Wbf, (const float4*)x, (uint4*)xbf);

  // 2. scatter-add active weights directly in bf16 (packed atomic)
  scatter_bf16<<<(nnz + 255) / 256, 256, 0, stream>>>(
      wvals, idx, idx + nnz, mk, (unsigned*)Wbf, nnz);

  // 3. y = x @ W^T
  gemm_bt_ra<<<256, 512, 0, stream>>>(xbf, Wbf, (float*)d_out);
}